// Round 1
// baseline (104.385 us; speedup 1.0000x reference)
//
#include <hip/hip_runtime.h>
#include <math.h>

#define JT 256
#define BLOCK 256

__global__ __launch_bounds__(BLOCK) void lddt_pairs(
    const float* __restrict__ pred, const float* __restrict__ truec,
    const int* __restrict__ isdna, const int* __restrict__ isrna,
    float* __restrict__ ws, int N)
{
  const int b  = blockIdx.z;
  const int i  = blockIdx.y * BLOCK + threadIdx.x;
  const int j0 = blockIdx.x * JT;

  __shared__ float4 sp[JT];   // pred x,y,z + nuc flag (w>0 means nucleic)
  __shared__ float4 st[JT];   // true x,y,z

  {
    const int j = j0 + threadIdx.x;
    const size_t base = (size_t)b * N + j;
    const float* pp = pred  + base * 3;
    const float* tt = truec + base * 3;
    const float nuc = ((isdna[base] | isrna[base]) != 0) ? 1.0f : -1.0f;
    sp[threadIdx.x] = make_float4(pp[0], pp[1], pp[2], nuc);
    st[threadIdx.x] = make_float4(tt[0], tt[1], tt[2], 0.0f);
  }
  __syncthreads();

  const size_t ibase = (size_t)b * N + i;
  const float pix = pred[ibase*3+0], piy = pred[ibase*3+1], piz = pred[ibase*3+2];
  const float tix = truec[ibase*3+0], tiy = truec[ibase*3+1], tiz = truec[ibase*3+2];
  const bool nuci = ((isdna[ibase] | isrna[ibase]) != 0);

  // exp(-0.5), exp(-1), exp(-2), exp(-4): sigmoid(a-d) = 1/(1 + e^d * e^-a)
  const float C0 = 0.606530659712633f;
  const float C1 = 0.367879441171442f;
  const float C2 = 0.135335283236613f;
  const float C3 = 0.018315638888734f;

  float sum = 0.0f, cnt = 0.0f;

#pragma unroll 4
  for (int jj = 0; jj < JT; ++jj) {
    const float4 P = sp[jj];
    const float4 T = st[jj];
    // pred distance
    float dx = P.x - pix, dy = P.y - piy, dz = P.z - piz;
    float d2p = fmaf(dx, dx, fmaf(dy, dy, dz * dz));
    float dp  = __builtin_amdgcn_sqrtf(d2p);
    // true distance
    float ex = T.x - tix, ey = T.y - tiy, ez = T.z - tiz;
    float d2t = fmaf(ex, ex, fmaf(ey, ey, ez * ez));
    float dt  = __builtin_amdgcn_sqrtf(d2t);

    float diff = fabsf(dt - dp);
    float e = __expf(diff);                 // ONE exp serves all 4 sigmoids
    float u0 = fmaf(e, C0, 1.0f);
    float u1 = fmaf(e, C1, 1.0f);
    float u2 = fmaf(e, C2, 1.0f);
    float u3 = fmaf(e, C3, 1.0f);
    // 1/u0 + 1/u1 + 1/u2 + 1/u3 with a single reciprocal
    float s01 = u0 + u1, p01 = u0 * u1;
    float s23 = u2 + u3, p23 = u2 * u3;
    float num = fmaf(s01, p23, s23 * p01);
    float den = p01 * p23;
    float eps4 = num * __builtin_amdgcn_rcpf(den);

    bool nucpair = nuci && (P.w > 0.0f);
    float cutoff = nucpair ? 30.0f : 15.0f;
    bool inc = (dt < cutoff) && ((j0 + jj) != i);
    float m = inc ? 1.0f : 0.0f;
    sum = fmaf(eps4, m, sum);
    cnt += m;
  }
  sum *= 0.25f;

  // intra-wave butterfly reduce (wave64)
  for (int off = 32; off > 0; off >>= 1) {
    sum += __shfl_down(sum, off, 64);
    cnt += __shfl_down(cnt, off, 64);
  }
  __shared__ float redS[BLOCK/64], redC[BLOCK/64];
  const int wave = threadIdx.x >> 6;
  const int lane = threadIdx.x & 63;
  if (lane == 0) { redS[wave] = sum; redC[wave] = cnt; }
  __syncthreads();
  if (threadIdx.x == 0) {
    float S = 0.f, C = 0.f;
    for (int w = 0; w < BLOCK/64; ++w) { S += redS[w]; C += redC[w]; }
    atomicAdd(&ws[b], S);                 // per-batch eps sum
    atomicAdd(&ws[gridDim.z + b], C);     // per-batch count
  }
}

__global__ void lddt_final(const float* __restrict__ ws, float* __restrict__ out, int B)
{
  if (threadIdx.x == 0 && blockIdx.x == 0) {
    float acc = 0.0f;
    for (int b = 0; b < B; ++b) {
      acc += ws[b] / fmaxf(ws[B + b], 1.0f);
    }
    out[0] = 1.0f - acc / (float)B;
  }
}

extern "C" void kernel_launch(void* const* d_in, const int* in_sizes, int n_in,
                              void* d_out, int out_size, void* d_ws, size_t ws_size,
                              hipStream_t stream)
{
  const float* pred  = (const float*)d_in[0];
  const float* truec = (const float*)d_in[1];
  const int*   isdna = (const int*)d_in[2];
  const int*   isrna = (const int*)d_in[3];
  float* out = (float*)d_out;
  float* ws  = (float*)d_ws;

  const int B = 2;
  const int N = in_sizes[2] / B;   // 4096

  hipMemsetAsync(ws, 0, sizeof(float) * 2 * B, stream);

  dim3 grid(N / JT, N / BLOCK, B);
  lddt_pairs<<<grid, BLOCK, 0, stream>>>(pred, truec, isdna, isrna, ws, N);
  lddt_final<<<1, 64, 0, stream>>>(ws, out, B);
}

// Round 2
// 85.315 us; speedup vs baseline: 1.2235x; 1.2235x over previous
//
#include <hip/hip_runtime.h>
#include <math.h>

#define BLOCK 64   // one wave per block; i-tile = j-tile = 64

__global__ __launch_bounds__(BLOCK) void lddt_pairs(
    const float* __restrict__ pred, const float* __restrict__ truec,
    const int* __restrict__ isdna, const int* __restrict__ isrna,
    float* __restrict__ ws, int N, int C, int T)
{
  // Map linear tile id -> upper-triangle (ic, jc), jc >= ic.
  const int t = blockIdx.x;
  const int b = blockIdx.y;
  const float fC = (float)C;
  int ic = (int)((2.0f*fC + 1.0f -
                  sqrtf((2.0f*fC + 1.0f)*(2.0f*fC + 1.0f) - 8.0f*(float)t)) * 0.5f);
  if (ic > C - 1) ic = C - 1;
  if (ic < 0) ic = 0;
  while (ic > 0 && t < ic*C - ((ic*(ic-1)) >> 1)) --ic;
  while (t >= (ic+1)*C - (((ic+1)*ic) >> 1)) ++ic;
  const int jc = ic + t - (ic*C - ((ic*(ic-1)) >> 1));
  const bool diag = (ic == jc);

  __shared__ float4 sp[BLOCK];  // pred x,y,z ; w = cutoff-if-i-is-nuc (30 or 15)
  __shared__ float4 st[BLOCK];  // true x,y,z

  const int tid = threadIdx.x;
  {
    const int j = jc * BLOCK + tid;
    const size_t base = (size_t)b * N + j;
    const float* pp = pred  + base * 3;
    const float* tt = truec + base * 3;
    const float cutj = ((isdna[base] | isrna[base]) != 0) ? 30.0f : 15.0f;
    sp[tid] = make_float4(pp[0], pp[1], pp[2], cutj);
    st[tid] = make_float4(tt[0], tt[1], tt[2], 0.0f);
  }

  const int i = ic * BLOCK + tid;
  const size_t ibase = (size_t)b * N + i;
  const float pix = pred[ibase*3+0], piy = pred[ibase*3+1], piz = pred[ibase*3+2];
  const float tix = truec[ibase*3+0], tiy = truec[ibase*3+1], tiz = truec[ibase*3+2];
  const bool nuci = ((isdna[ibase] | isrna[ibase]) != 0);

  __syncthreads();

  // sigmoid(a - d) = 1 / (1 + e^d * e^-a); constants e^-a for a = .5, 1, 2, 4
  const float C0 = 0.606530659712633f;
  const float C1 = 0.367879441171442f;
  const float C2 = 0.135335283236613f;
  const float C3 = 0.018315638888734f;
  const float L2E = 1.44269504088896f;

  float sum = 0.0f;
  int   cnt = 0;

  if (!diag) {
#pragma unroll 4
    for (int jj = 0; jj < BLOCK; ++jj) {
      const float4 P = sp[jj];
      const float4 T4 = st[jj];
      float dx = P.x - pix, dy = P.y - piy, dz = P.z - piz;
      float dp = __builtin_amdgcn_sqrtf(fmaf(dx, dx, fmaf(dy, dy, dz * dz)));
      float ex = T4.x - tix, ey = T4.y - tiy, ez = T4.z - tiz;
      float dt = __builtin_amdgcn_sqrtf(fmaf(ex, ex, fmaf(ey, ey, ez * ez)));

      float e = __builtin_amdgcn_exp2f(fabsf(dt - dp) * L2E);
      float u0 = fmaf(e, C0, 1.0f);
      float u1 = fmaf(e, C1, 1.0f);
      float u2 = fmaf(e, C2, 1.0f);
      float u3 = fmaf(e, C3, 1.0f);
      float s01 = u0 + u1, p01 = u0 * u1;
      float s23 = u2 + u3, p23 = u2 * u3;
      float num = fmaf(s01, p23, s23 * p01);
      float eps4 = num * __builtin_amdgcn_rcpf(p01 * p23);

      float cutoff = nuci ? P.w : 15.0f;
      bool inc = (dt < cutoff);
      unsigned long long bal = __ballot(inc);
      cnt += (int)__popcll(bal);
      sum += inc ? eps4 : 0.0f;
    }
  } else {
#pragma unroll 4
    for (int jj = 0; jj < BLOCK; ++jj) {
      const float4 P = sp[jj];
      const float4 T4 = st[jj];
      float dx = P.x - pix, dy = P.y - piy, dz = P.z - piz;
      float dp = __builtin_amdgcn_sqrtf(fmaf(dx, dx, fmaf(dy, dy, dz * dz)));
      float ex = T4.x - tix, ey = T4.y - tiy, ez = T4.z - tiz;
      float dt = __builtin_amdgcn_sqrtf(fmaf(ex, ex, fmaf(ey, ey, ez * ez)));

      float e = __builtin_amdgcn_exp2f(fabsf(dt - dp) * L2E);
      float u0 = fmaf(e, C0, 1.0f);
      float u1 = fmaf(e, C1, 1.0f);
      float u2 = fmaf(e, C2, 1.0f);
      float u3 = fmaf(e, C3, 1.0f);
      float s01 = u0 + u1, p01 = u0 * u1;
      float s23 = u2 + u3, p23 = u2 * u3;
      float num = fmaf(s01, p23, s23 * p01);
      float eps4 = num * __builtin_amdgcn_rcpf(p01 * p23);

      float cutoff = nuci ? P.w : 15.0f;
      bool inc = (dt < cutoff) && (jj != tid);
      unsigned long long bal = __ballot(inc);
      cnt += (int)__popcll(bal);
      sum += inc ? eps4 : 0.0f;
    }
  }

  // wave64 butterfly reduce on sum (cnt is already wave-uniform via ballot)
  for (int off = 32; off > 0; off >>= 1)
    sum += __shfl_down(sum, off, 64);

  if (tid == 0) {
    const float w = diag ? 1.0f : 2.0f;
    const int p = b * T + t;
    ws[p]         = 0.25f * w * sum;     // eps partial
    ws[(size_t)gridDim.y * T + p] = w * (float)cnt;  // count partial
  }
}

__global__ __launch_bounds__(256) void lddt_final(
    const float* __restrict__ ws, float* __restrict__ out, int B, int T)
{
  __shared__ float rs[4], rc[4];
  float acc = 0.0f;
  for (int b = 0; b < B; ++b) {
    float s = 0.0f, c = 0.0f;
    for (int k = threadIdx.x; k < T; k += 256) {
      s += ws[b * T + k];
      c += ws[(size_t)B * T + b * T + k];
    }
    for (int off = 32; off > 0; off >>= 1) {
      s += __shfl_down(s, off, 64);
      c += __shfl_down(c, off, 64);
    }
    const int wave = threadIdx.x >> 6, lane = threadIdx.x & 63;
    if (lane == 0) { rs[wave] = s; rc[wave] = c; }
    __syncthreads();
    if (threadIdx.x == 0) {
      float S  = rs[0] + rs[1] + rs[2] + rs[3];
      float Cc = rc[0] + rc[1] + rc[2] + rc[3];
      acc += S / fmaxf(Cc, 1.0f);
    }
    __syncthreads();
  }
  if (threadIdx.x == 0) out[0] = 1.0f - acc / (float)B;
}

extern "C" void kernel_launch(void* const* d_in, const int* in_sizes, int n_in,
                              void* d_out, int out_size, void* d_ws, size_t ws_size,
                              hipStream_t stream)
{
  const float* pred  = (const float*)d_in[0];
  const float* truec = (const float*)d_in[1];
  const int*   isdna = (const int*)d_in[2];
  const int*   isrna = (const int*)d_in[3];
  float* out = (float*)d_out;
  float* ws  = (float*)d_ws;

  const int B = 2;
  const int N = in_sizes[2] / B;       // 4096
  const int C = N / BLOCK;             // 64 chunks
  const int T = C * (C + 1) / 2;       // 2080 triangle tiles

  dim3 grid(T, B);
  lddt_pairs<<<grid, BLOCK, 0, stream>>>(pred, truec, isdna, isrna, ws, N, C, T);
  lddt_final<<<1, 256, 0, stream>>>(ws, out, B, T);
}